// Round 8
// baseline (295.245 us; speedup 1.0000x reference)
//
#include <hip/hip_runtime.h>
#include <hip/hip_bf16.h>

#define BATCH 8
#define CCH 1024
#define NHW 4096
#define SCALE 5.0f   // 1/TEMPERATURE
#define ROWS (BATCH * CCH)
#define NTILES 72            // 128x64 upper-triangle tiles per batch
#define NTICK (BATCH * NTILES)   // 576 work items
#define GRID_G 512           // exactly 2 blocks/CU -> balanced makespan

typedef unsigned char u8;
typedef unsigned int u32;
typedef __attribute__((ext_vector_type(4))) float float4v;
typedef __attribute__((ext_vector_type(4))) u32 uint4v;

__device__ __forceinline__ void async_load16(const void* gsrc, void* ldst) {
    __builtin_amdgcn_global_load_lds(
        (__attribute__((address_space(1))) void*)gsrc,
        (__attribute__((address_space(3))) void*)ldst,
        16, 0, 0);
}

// pack 4 floats -> 4 OCP e4m3 bytes
__device__ __forceinline__ u32 pk4_fp8(float a, float b, float c, float d) {
    u32 v = __builtin_amdgcn_cvt_pk_fp8_f32(a, b, 0, false);
    v = __builtin_amdgcn_cvt_pk_fp8_f32(c, d, v, true);
    return v;
}

__device__ __forceinline__ float ssq4_fp8(u32 q) {
    float d0 = __builtin_amdgcn_cvt_f32_fp8(q, 0);
    float d1 = __builtin_amdgcn_cvt_f32_fp8(q, 1);
    float d2 = __builtin_amdgcn_cvt_f32_fp8(q, 2);
    float d3 = __builtin_amdgcn_cvt_f32_fp8(q, 3);
    return d0 * d0 + d1 * d1 + d2 * d2 + d3 * d3;
}

// One block per row: quantize x -> fp8, diag = 5*sum(q(x)^2) from QUANTIZED
// values (so the MFMA diagonal dot cancels), zero l_acc, zero queue counters.
template <bool CONVERT>
__global__ __launch_bounds__(256) void prep_kernel(const float* __restrict__ x,
                                                   u8* __restrict__ xq,
                                                   float* __restrict__ diag,
                                                   float* __restrict__ l_acc,
                                                   int* __restrict__ counters) {
    const int row = blockIdx.x;          // 0..8191
    const int tid = threadIdx.x;
    const float* src = x + (size_t)row * NHW;
    float ssum = 0.f;
#pragma unroll
    for (int p = 0; p < 4; ++p) {
        const int idx = p * 1024 + tid * 4;
        float4 v = *(const float4*)(src + idx);
        const u32 q = pk4_fp8(v.x, v.y, v.z, v.w);
        ssum += ssq4_fp8(q);
        if (CONVERT) *(u32*)(xq + (size_t)row * NHW + idx) = q;
    }
#pragma unroll
    for (int m = 1; m < 64; m <<= 1) ssum += __shfl_xor(ssum, m);
    __shared__ float red[4];
    if ((tid & 63) == 0) red[tid >> 6] = ssum;
    __syncthreads();
    if (tid == 0) {
        diag[row] = (red[0] + red[1] + red[2] + red[3]) * SCALE;
        l_acc[row] = 0.f;
        if (row == 0) { counters[0] = 0; counters[1] = 0; }  // queue, done
    }
}

// Symmetric Gram, fp8 e4m3, 128x64 tiles over upper triangle (bj2 >= 2*bi),
// BK=128, double-buffered prefetch (R7). NEW: 512 persistent blocks pull tiles
// from an atomic work queue (balanced 2.25 tiles/CU over 2 slots/CU instead of
// static 2-vs-3 blocks/CU imbalance), and the last block to finish runs the
// finalize reduction inline (release/acquire via done-counter + threadfence).
template <bool QSRC>
__global__ __launch_bounds__(256) void gram_kernel(const u8* __restrict__ Xq,
                                                   const float* __restrict__ Xf,
                                                   const float* __restrict__ diag,
                                                   float* __restrict__ l_acc,
                                                   float* __restrict__ num,
                                                   int* __restrict__ counters,
                                                   float* __restrict__ out) {
    __shared__ __align__(16) u8 As[2][16384];   // 128 rows * 128 B, x2
    __shared__ __align__(16) u8 Bs[2][8192];    //  64 rows * 128 B, x2
    __shared__ int s_ticket;
    __shared__ float s_red[4];

    const int tid  = threadIdx.x;
    const int lane = tid & 63;
    const int w    = tid >> 6;       // wave 0..3
    const int wm   = w >> 1;         // wave row-half (64 rows)
    const int wn   = w & 1;          // wave col-half (32 cols)

    // Staging: instr covers 8 rows x 8 slots. lane l -> row l>>3, slot l&7,
    // source kchunk = (l&7) ^ (l>>3).
    const int st_r  = lane >> 3;               // 0..7
    const int st_kc = (lane & 7) ^ st_r;       // source 16B-chunk

    const int q_  = lane >> 4;    // row-quad 0..3
    const int cl  = lane & 15;    // col within 16

    for (;;) {
        if (tid == 0) s_ticket = atomicAdd(counters + 0, 1);
        __syncthreads();
        const int tk = s_ticket;
        if (tk >= NTICK) break;

        const int b = tk & 7;            // batch
        const int t = tk >> 3;           // 0..71 upper-tile index
        int bi = 0;
#pragma unroll
        for (int i = 7; i >= 1; --i) {   // off(bi) = bi*(17-bi), increasing
            if (t >= i * (17 - i)) { bi = i; break; }
        }
        const int bj2 = 2 * bi + (t - bi * (17 - bi));   // 64-col block, 0..15
        const bool aliasB = (bj2 == 2 * bi) || (bj2 == 2 * bi + 1);

        const u8*    pA  = nullptr; const u8*    pB  = nullptr;
        const float* pAf = nullptr; const float* pBf = nullptr;
        if (QSRC) {
            const u8* baseX = Xq + (size_t)b * CCH * NHW;
            pA = baseX + (size_t)(bi * 128 + w * 32 + st_r) * NHW + st_kc * 16;
            pB = baseX + (size_t)(bj2 * 64 + w * 16 + st_r) * NHW + st_kc * 16;
        } else {
            const float* baseXf = Xf + (size_t)b * CCH * NHW;
            pAf = baseXf + (size_t)(bi * 128 + w * 32 + st_r) * NHW + st_kc * 16;
            pBf = baseXf + (size_t)(bj2 * 64 + w * 16 + st_r) * NHW + st_kc * 16;
        }

        auto stage = [&](int buf, int K0) {
            if (QSRC) {
#pragma unroll
                for (int t8 = 0; t8 < 4; ++t8)     // A: 32 rows per wave
                    async_load16(pA + (size_t)(t8 * 8) * NHW + K0,
                                 As[buf] + (size_t)(w * 32 + t8 * 8) * 128);
                if (!aliasB) {
#pragma unroll
                    for (int t8 = 0; t8 < 2; ++t8) // B: 16 rows per wave
                        async_load16(pB + (size_t)(t8 * 8) * NHW + K0,
                                     Bs[buf] + (size_t)(w * 16 + t8 * 8) * 128);
                }
            } else {
#pragma unroll
                for (int t8 = 0; t8 < 4; ++t8) {
                    const float* s = pAf + (size_t)(t8 * 8) * NHW + K0;
                    float4 f0 = *(const float4*)(s);
                    float4 f1 = *(const float4*)(s + 4);
                    float4 f2 = *(const float4*)(s + 8);
                    float4 f3 = *(const float4*)(s + 12);
                    uint4v d;
                    d.x = pk4_fp8(f0.x, f0.y, f0.z, f0.w);
                    d.y = pk4_fp8(f1.x, f1.y, f1.z, f1.w);
                    d.z = pk4_fp8(f2.x, f2.y, f2.z, f2.w);
                    d.w = pk4_fp8(f3.x, f3.y, f3.z, f3.w);
                    *(uint4v*)(As[buf] + (size_t)(w * 32 + t8 * 8 + st_r) * 128 + (lane & 7) * 16) = d;
                }
                if (!aliasB) {
#pragma unroll
                    for (int t8 = 0; t8 < 2; ++t8) {
                        const float* s = pBf + (size_t)(t8 * 8) * NHW + K0;
                        float4 f0 = *(const float4*)(s);
                        float4 f1 = *(const float4*)(s + 4);
                        float4 f2 = *(const float4*)(s + 8);
                        float4 f3 = *(const float4*)(s + 12);
                        uint4v d;
                        d.x = pk4_fp8(f0.x, f0.y, f0.z, f0.w);
                        d.y = pk4_fp8(f1.x, f1.y, f1.z, f1.w);
                        d.z = pk4_fp8(f2.x, f2.y, f2.z, f2.w);
                        d.w = pk4_fp8(f3.x, f3.y, f3.z, f3.w);
                        *(uint4v*)(Bs[buf] + (size_t)(w * 16 + t8 * 8 + st_r) * 128 + (lane & 7) * 16) = d;
                    }
                }
            }
        };

        float4v acc[4][2] = {};

        stage(0, 0);
        __syncthreads();                 // publish buffer 0

        for (int i = 0; i < NHW / 128; ++i) {
            const int cur = i & 1;
            const int K0n = (i + 1) * 128;
            if (K0n < NHW) stage(cur ^ 1, K0n);   // prefetch BEFORE compute

            const u8* Ab = As[cur];
            const u8* Bb = aliasB ? (Ab + (size_t)(bj2 - 2 * bi) * 64 * 128) : Bs[cur];
            const int rl = lane & 15;
#pragma unroll
            for (int s = 0; s < 4; ++s) {          // 4 k-steps of 32 elements
                const int cbase = 2 * s + (q_ >> 1);           // 16B chunk 0..7
                const int boff  = (int)((cbase ^ (rl & 7)) * 16 + (q_ & 1) * 8);
                long af[4], bf[2];
#pragma unroll
                for (int mt = 0; mt < 4; ++mt)
                    af[mt] = *(const long*)(Ab + (size_t)(wm * 64 + mt * 16 + rl) * 128 + boff);
#pragma unroll
                for (int nt = 0; nt < 2; ++nt)
                    bf[nt] = *(const long*)(Bb + (size_t)(wn * 32 + nt * 16 + rl) * 128 + boff);
#pragma unroll
                for (int mt = 0; mt < 4; ++mt)
#pragma unroll
                    for (int nt = 0; nt < 2; ++nt)
                        acc[mt][nt] = __builtin_amdgcn_mfma_f32_16x16x32_fp8_fp8(af[mt], bf[nt], acc[mt][nt], 0, 0, 0);
            }
            __syncthreads();   // publish prefetched buffer
        }

        // ---- Epilogue for this tile ----
        const int rowbase = bi * 128 + wm * 64;
        const int colbase = bj2 * 64 + wn * 32;
        const float* dgb = diag + b * CCH;
        float* lb = l_acc + b * CCH;

#pragma unroll
        for (int mt = 0; mt < 4; ++mt) {
#pragma unroll
            for (int reg = 0; reg < 4; ++reg) {
                const int gr = rowbase + mt * 16 + q_ * 4 + reg;
                const float dg = dgb[gr];
                float s = 0.f;
#pragma unroll
                for (int nt = 0; nt < 2; ++nt) {
                    const int gc = colbase + nt * 16 + cl;
                    const float e = __expf(acc[mt][nt][reg] * SCALE - dg);
                    if (gr <= gc) s += e;
                    if (gr == gc) num[b * CCH + gr] = e;
                }
                s += __shfl_xor(s, 1);
                s += __shfl_xor(s, 2);
                s += __shfl_xor(s, 4);
                s += __shfl_xor(s, 8);
                if (cl == 0) atomicAdd(lb + gr, s);
            }
        }

#pragma unroll
        for (int nt = 0; nt < 2; ++nt) {
            const int gc = colbase + nt * 16 + cl;
            const float dgc = dgb[gc];
            float s = 0.f;
#pragma unroll
            for (int mt = 0; mt < 4; ++mt) {
#pragma unroll
                for (int reg = 0; reg < 4; ++reg) {
                    const int gr = rowbase + mt * 16 + q_ * 4 + reg;
                    if (gr < gc) s += __expf(acc[mt][nt][reg] * SCALE - dgc);
                }
            }
            s += __shfl_xor(s, 16);
            s += __shfl_xor(s, 32);
            if (lane < 16) atomicAdd(lb + gc, s);
        }
        // loop continues: next ticket (s_ticket rewrite is ordered by the
        // __syncthreads at the top of the next iteration)
    }

    // ---- Completion counter; last block finalizes ----
    __syncthreads();
    if (tid == 0) {
        __threadfence();                       // release this block's stores
        const int old = atomicAdd(counters + 1, 1);
        s_ticket = (old == GRID_G - 1) ? 1 : 0;
    }
    __syncthreads();
    if (s_ticket) {
        __threadfence();                       // acquire all blocks' stores
        float s = 0.f;
        for (int r = tid; r < ROWS; r += 256) {
            const float d = num[r] / l_acc[r];
            s += -__logf(d + 1e-10f);
        }
#pragma unroll
        for (int m = 1; m < 64; m <<= 1) s += __shfl_xor(s, m);
        if ((tid & 63) == 0) s_red[tid >> 6] = s;
        __syncthreads();
        if (tid == 0)
            out[0] = (s_red[0] + s_red[1] + s_red[2] + s_red[3]) * (1.0f / (float)ROWS);
    }
}

extern "C" void kernel_launch(void* const* d_in, const int* in_sizes, int n_in,
                              void* d_out, int out_size, void* d_ws, size_t ws_size,
                              hipStream_t stream) {
    const float* x = (const float*)d_in[0];
    float* out = (float*)d_out;

    const size_t xq_bytes   = (size_t)BATCH * CCH * NHW;      // 33554432 (fp8)
    const size_t stat_bytes = (size_t)ROWS * 4;               // 32768
    const bool fast = ws_size >= xq_bytes + 3 * stat_bytes + 64;

    if (fast) {
        u8*    xq    = (u8*)d_ws;
        float* diag  = (float*)((char*)d_ws + xq_bytes);
        float* l_acc = diag + ROWS;
        float* num   = l_acc + ROWS;
        int*   cnt   = (int*)(num + ROWS);
        prep_kernel<true><<<ROWS, 256, 0, stream>>>(x, xq, diag, l_acc, cnt);
        gram_kernel<true><<<GRID_G, 256, 0, stream>>>(xq, nullptr, diag, l_acc, num, cnt, out);
    } else {
        float* diag  = (float*)d_ws;
        float* l_acc = diag + ROWS;
        float* num   = l_acc + ROWS;
        int*   cnt   = (int*)(num + ROWS);
        prep_kernel<false><<<ROWS, 256, 0, stream>>>(x, nullptr, diag, l_acc, cnt);
        gram_kernel<false><<<GRID_G, 256, 0, stream>>>(nullptr, x, diag, l_acc, num, cnt, out);
    }
}

// Round 9
// 249.305 us; speedup vs baseline: 1.1843x; 1.1843x over previous
//
#include <hip/hip_runtime.h>
#include <hip/hip_bf16.h>

#define BATCH 8
#define CCH 1024
#define NHW 4096
#define SCALE 5.0f   // 1/TEMPERATURE
#define ROWS (BATCH * CCH)
#define NTILES 72            // 128x64 upper-triangle tiles per batch
#define GRID_G (BATCH * NTILES)  // 576 blocks, bid&7 = batch -> XCD affinity

typedef unsigned char u8;
typedef unsigned int u32;
typedef __attribute__((ext_vector_type(4))) float float4v;
typedef __attribute__((ext_vector_type(2))) long long2v;

__device__ __forceinline__ void async_load16(const void* gsrc, void* ldst) {
    __builtin_amdgcn_global_load_lds(
        (__attribute__((address_space(1))) void*)gsrc,
        (__attribute__((address_space(3))) void*)ldst,
        16, 0, 0);
}

// pack 4 floats -> 4 OCP e4m3 bytes
__device__ __forceinline__ u32 pk4_fp8(float a, float b, float c, float d) {
    u32 v = __builtin_amdgcn_cvt_pk_fp8_f32(a, b, 0, false);
    v = __builtin_amdgcn_cvt_pk_fp8_f32(c, d, v, true);
    return v;
}

__device__ __forceinline__ float ssq4_fp8(u32 q) {
    float d0 = __builtin_amdgcn_cvt_f32_fp8(q, 0);
    float d1 = __builtin_amdgcn_cvt_f32_fp8(q, 1);
    float d2 = __builtin_amdgcn_cvt_f32_fp8(q, 2);
    float d3 = __builtin_amdgcn_cvt_f32_fp8(q, 3);
    return d0 * d0 + d1 * d1 + d2 * d2 + d3 * d3;
}

// K-permutation within each 128-element span: logical 8B-unit L -> physical
// position P, so that physical chunk c = sp*4+q (16B) holds a lane's a/b-frags
// for k-steps s=2sp (lo 8B) and s=2sp+1 (hi 8B). Gram is invariant to any
// k-permutation applied to both operands (same matrix here).
__device__ __forceinline__ int kperm(int L) {
    return ((L >> 3) << 3) + ((L & 3) << 1) + ((L >> 2) & 1);
}

// One block per row: quantize x -> fp8 in PERMUTED unit order, diag =
// 5*sum(q(x)^2) from the QUANTIZED values, zero l_acc + done counter.
template <bool CONVERT>
__global__ __launch_bounds__(256) void prep_kernel(const float* __restrict__ x,
                                                   u8* __restrict__ xq,
                                                   float* __restrict__ diag,
                                                   float* __restrict__ l_acc,
                                                   int* __restrict__ counters) {
    const int row = blockIdx.x;          // 0..8191
    const int tid = threadIdx.x;
    const float* src = x + (size_t)row * NHW;
    float ssum = 0.f;
#pragma unroll
    for (int p = 0; p < 4; ++p) {
        const int idx = p * 1024 + tid * 4;      // float index within row
        float4 v = *(const float4*)(src + idx);
        const u32 q = pk4_fp8(v.x, v.y, v.z, v.w);
        ssum += ssq4_fp8(q);
        if (CONVERT) {
            const int span = idx >> 7;           // 128-elem span
            const int kin  = idx & 127;
            const int P    = kperm(kin >> 3);    // permuted 8B-unit position
            const int sub  = kin & 7;            // 0 or 4 within unit
            *(u32*)(xq + (size_t)row * NHW + span * 128 + P * 8 + sub) = q;
        }
    }
#pragma unroll
    for (int m = 1; m < 64; m <<= 1) ssum += __shfl_xor(ssum, m);
    __shared__ float red[4];
    if ((tid & 63) == 0) red[tid >> 6] = ssum;
    __syncthreads();
    if (tid == 0) {
        diag[row] = (red[0] + red[1] + red[2] + red[3]) * SCALE;
        l_acc[row] = 0.f;
        if (row == 0) counters[0] = 0;           // done counter
    }
}

// Symmetric Gram, fp8 e4m3, 128x64 tiles over upper triangle (bj2 >= 2*bi),
// BK=128, double-buffered prefetch, STATIC grid with bid&7=batch (XCD L2
// affinity — R8 showed the dynamic queue thrashes L2: FETCH 116MB, HBM 1TB/s).
// Reads: K-permuted layout (see kperm) -> one ds_read_b128 per fragment-row
// per half-iter with chunk=(sp*4+q)^(rl&7) — the R2 pattern that measured
// SQ_LDS_BANK_CONFLICT==0 (fp8 b64 pattern measured 7.08M in R8).
// Last-finishing block runs the finalize reduction inline (fence + counter).
template <bool QSRC>
__global__ __launch_bounds__(256) void gram_kernel(const u8* __restrict__ Xq,
                                                   const float* __restrict__ Xf,
                                                   const float* __restrict__ diag,
                                                   float* __restrict__ l_acc,
                                                   float* __restrict__ num,
                                                   int* __restrict__ counters,
                                                   float* __restrict__ out) {
    __shared__ __align__(16) u8 As[2][16384];   // 128 rows * 128 B, x2
    __shared__ __align__(16) u8 Bs[2][8192];    //  64 rows * 128 B, x2
    __shared__ int s_flag;
    __shared__ float s_red[4];

    const int bid = blockIdx.x;
    const int b = bid & 7;           // batch -> XCD affinity
    const int t = bid >> 3;          // 0..71 upper-tile index

    int bi = 0;
#pragma unroll
    for (int i = 7; i >= 1; --i) {   // off(bi) = bi*(17-bi), increasing
        if (t >= i * (17 - i)) { bi = i; break; }
    }
    const int bj2 = 2 * bi + (t - bi * (17 - bi));   // 64-col block, 0..15
    const bool aliasB = (bj2 == 2 * bi) || (bj2 == 2 * bi + 1);

    const int tid  = threadIdx.x;
    const int lane = tid & 63;
    const int w    = tid >> 6;       // wave 0..3
    const int wm   = w >> 1;         // wave row-half (64 rows)
    const int wn   = w & 1;          // wave col-half (32 cols)

    // Staging: instr covers 8 rows x 8 chunks(16B). lane l -> row l>>3,
    // dest slot l&7, source chunk (l&7)^(l>>3)  [row-XOR placement].
    const int st_r  = lane >> 3;               // 0..7
    const int st_kc = (lane & 7) ^ st_r;       // source 16B-chunk

    const int q_  = lane >> 4;    // quad 0..3
    const int rl  = lane & 15;

    const u8*    pA  = nullptr; const u8*    pB  = nullptr;
    const float* pAf = nullptr; const float* pBf = nullptr;
    if (QSRC) {
        const u8* baseX = Xq + (size_t)b * CCH * NHW;
        pA = baseX + (size_t)(bi * 128 + w * 32 + st_r) * NHW + st_kc * 16;
        pB = baseX + (size_t)(bj2 * 64 + w * 16 + st_r) * NHW + st_kc * 16;
    } else {
        const float* baseXf = Xf + (size_t)b * CCH * NHW;
        pAf = baseXf + (size_t)(bi * 128 + w * 32 + st_r) * NHW;
        pBf = baseXf + (size_t)(bj2 * 64 + w * 16 + st_r) * NHW;
    }

    auto stage = [&](int buf, int K0) {
        if (QSRC) {
#pragma unroll
            for (int t8 = 0; t8 < 4; ++t8)     // A: 32 rows per wave
                async_load16(pA + (size_t)(t8 * 8) * NHW + K0,
                             As[buf] + (size_t)(w * 32 + t8 * 8) * 128);
            if (!aliasB) {
#pragma unroll
                for (int t8 = 0; t8 < 2; ++t8) // B: 16 rows per wave
                    async_load16(pB + (size_t)(t8 * 8) * NHW + K0,
                                 Bs[buf] + (size_t)(w * 16 + t8 * 8) * 128);
            }
        } else {
            // Fallback: quantize+permute from fp32 source into the same layout.
#pragma unroll
            for (int t8 = 0; t8 < 4; ++t8) {
                u8* drow = As[buf] + (size_t)(w * 32 + t8 * 8 + st_r) * 128 + (lane & 7) * 16;
#pragma unroll
                for (int h = 0; h < 2; ++h) {
                    const int p = 2 * st_kc + h;                    // physical 8B pos
                    const int L = ((p >> 3) << 3) + ((p & 1) << 2) + ((p & 7) >> 1);
                    const float* s = pAf + (size_t)(t8 * 8) * NHW + K0 + L * 8;
                    float4 f0 = *(const float4*)(s);
                    float4 f1 = *(const float4*)(s + 4);
                    ((u32*)(drow + h * 8))[0] = pk4_fp8(f0.x, f0.y, f0.z, f0.w);
                    ((u32*)(drow + h * 8))[1] = pk4_fp8(f1.x, f1.y, f1.z, f1.w);
                }
            }
            if (!aliasB) {
#pragma unroll
                for (int t8 = 0; t8 < 2; ++t8) {
                    u8* drow = Bs[buf] + (size_t)(w * 16 + t8 * 8 + st_r) * 128 + (lane & 7) * 16;
#pragma unroll
                    for (int h = 0; h < 2; ++h) {
                        const int p = 2 * st_kc + h;
                        const int L = ((p >> 3) << 3) + ((p & 1) << 2) + ((p & 7) >> 1);
                        const float* s = pBf + (size_t)(t8 * 8) * NHW + K0 + L * 8;
                        float4 f0 = *(const float4*)(s);
                        float4 f1 = *(const float4*)(s + 4);
                        ((u32*)(drow + h * 8))[0] = pk4_fp8(f0.x, f0.y, f0.z, f0.w);
                        ((u32*)(drow + h * 8))[1] = pk4_fp8(f1.x, f1.y, f1.z, f1.w);
                    }
                }
            }
        }
    };

    float4v acc[4][2] = {};

    stage(0, 0);
    __syncthreads();                 // publish buffer 0

    for (int i = 0; i < NHW / 128; ++i) {
        const int cur = i & 1;
        const int K0n = (i + 1) * 128;
        if (K0n < NHW) stage(cur ^ 1, K0n);   // prefetch BEFORE compute

        const u8* Ab = As[cur];
        const u8* Bb = aliasB ? (Ab + (size_t)(bj2 - 2 * bi) * 64 * 128) : Bs[cur];
#pragma unroll
        for (int sp = 0; sp < 2; ++sp) {
            const int boff = ((sp * 4 + q_) ^ (rl & 7)) * 16;   // R2 zero-conflict shape
            long2v a2[4], b2[2];
#pragma unroll
            for (int mt = 0; mt < 4; ++mt)
                a2[mt] = *(const long2v*)(Ab + (size_t)(wm * 64 + mt * 16 + rl) * 128 + boff);
#pragma unroll
            for (int nt = 0; nt < 2; ++nt)
                b2[nt] = *(const long2v*)(Bb + (size_t)(wn * 32 + nt * 16 + rl) * 128 + boff);
#pragma unroll
            for (int mt = 0; mt < 4; ++mt)
#pragma unroll
                for (int nt = 0; nt < 2; ++nt) {
                    acc[mt][nt] = __builtin_amdgcn_mfma_f32_16x16x32_fp8_fp8(a2[mt].x, b2[nt].x, acc[mt][nt], 0, 0, 0);
                    acc[mt][nt] = __builtin_amdgcn_mfma_f32_16x16x32_fp8_fp8(a2[mt].y, b2[nt].y, acc[mt][nt], 0, 0, 0);
                }
        }
        __syncthreads();   // publish prefetched buffer
    }

    // ---- Epilogue ----
    const int cl = rl;           // col within 16
    const int rowbase = bi * 128 + wm * 64;
    const int colbase = bj2 * 64 + wn * 32;
    const float* dgb = diag + b * CCH;
    float* lb = l_acc + b * CCH;

    // Row sums (upper-inclusive) + diagonal numerator
#pragma unroll
    for (int mt = 0; mt < 4; ++mt) {
#pragma unroll
        for (int reg = 0; reg < 4; ++reg) {
            const int gr = rowbase + mt * 16 + q_ * 4 + reg;
            const float dg = dgb[gr];
            float s = 0.f;
#pragma unroll
            for (int nt = 0; nt < 2; ++nt) {
                const int gc = colbase + nt * 16 + cl;
                const float e = __expf(acc[mt][nt][reg] * SCALE - dg);
                if (gr <= gc) s += e;
                if (gr == gc) num[b * CCH + gr] = e;
            }
            s += __shfl_xor(s, 1);
            s += __shfl_xor(s, 2);
            s += __shfl_xor(s, 4);
            s += __shfl_xor(s, 8);
            if (cl == 0) atomicAdd(lb + gr, s);
        }
    }

    // Column sums (strictly-upper -> transposed contribution)
#pragma unroll
    for (int nt = 0; nt < 2; ++nt) {
        const int gc = colbase + nt * 16 + cl;
        const float dgc = dgb[gc];
        float s = 0.f;
#pragma unroll
        for (int mt = 0; mt < 4; ++mt) {
#pragma unroll
            for (int reg = 0; reg < 4; ++reg) {
                const int gr = rowbase + mt * 16 + q_ * 4 + reg;
                if (gr < gc) s += __expf(acc[mt][nt][reg] * SCALE - dgc);
            }
        }
        s += __shfl_xor(s, 16);
        s += __shfl_xor(s, 32);
        if (lane < 16) atomicAdd(lb + gc, s);
    }

    // ---- Completion counter; last block finalizes ----
    __syncthreads();
    if (tid == 0) {
        __threadfence();                       // release this block's stores
        const int old = atomicAdd(counters + 0, 1);
        s_flag = (old == GRID_G - 1) ? 1 : 0;
    }
    __syncthreads();
    if (s_flag) {
        __threadfence();                       // acquire all blocks' stores
        float s = 0.f;
        for (int r = tid; r < ROWS; r += 256) {
            const float d = num[r] / l_acc[r];
            s += -__logf(d + 1e-10f);
        }
#pragma unroll
        for (int m = 1; m < 64; m <<= 1) s += __shfl_xor(s, m);
        if ((tid & 63) == 0) s_red[tid >> 6] = s;
        __syncthreads();
        if (tid == 0)
            out[0] = (s_red[0] + s_red[1] + s_red[2] + s_red[3]) * (1.0f / (float)ROWS);
    }
}

extern "C" void kernel_launch(void* const* d_in, const int* in_sizes, int n_in,
                              void* d_out, int out_size, void* d_ws, size_t ws_size,
                              hipStream_t stream) {
    const float* x = (const float*)d_in[0];
    float* out = (float*)d_out;

    const size_t xq_bytes   = (size_t)BATCH * CCH * NHW;      // 33554432 (fp8)
    const size_t stat_bytes = (size_t)ROWS * 4;               // 32768
    const bool fast = ws_size >= xq_bytes + 3 * stat_bytes + 64;

    if (fast) {
        u8*    xq    = (u8*)d_ws;
        float* diag  = (float*)((char*)d_ws + xq_bytes);
        float* l_acc = diag + ROWS;
        float* num   = l_acc + ROWS;
        int*   cnt   = (int*)(num + ROWS);
        prep_kernel<true><<<ROWS, 256, 0, stream>>>(x, xq, diag, l_acc, cnt);
        gram_kernel<true><<<GRID_G, 256, 0, stream>>>(xq, nullptr, diag, l_acc, num, cnt, out);
    } else {
        float* diag  = (float*)d_ws;
        float* l_acc = diag + ROWS;
        float* num   = l_acc + ROWS;
        int*   cnt   = (int*)(num + ROWS);
        prep_kernel<false><<<ROWS, 256, 0, stream>>>(x, nullptr, diag, l_acc, cnt);
        gram_kernel<false><<<GRID_G, 256, 0, stream>>>(nullptr, x, diag, l_acc, num, cnt, out);
    }
}

// Round 10
// 247.697 us; speedup vs baseline: 1.1920x; 1.0065x over previous
//
#include <hip/hip_runtime.h>
#include <hip/hip_bf16.h>

#define BATCH 8
#define CCH 1024
#define NHW 4096
#define SCALE 5.0f   // 1/TEMPERATURE
#define ROWS (BATCH * CCH)
#define NTILES 72            // 128x64 upper-triangle tiles per batch
#define GRID_G (BATCH * NTILES)  // 576 blocks, bid&7 = batch -> XCD affinity

typedef unsigned char u8;
typedef unsigned int u32;
typedef __attribute__((ext_vector_type(4))) float float4v;
typedef __attribute__((ext_vector_type(4))) u32 uint4v;

__device__ __forceinline__ void async_load16(const void* gsrc, void* ldst) {
    __builtin_amdgcn_global_load_lds(
        (__attribute__((address_space(1))) void*)gsrc,
        (__attribute__((address_space(3))) void*)ldst,
        16, 0, 0);
}

// pack 4 floats -> 4 OCP e4m3 bytes
__device__ __forceinline__ u32 pk4_fp8(float a, float b, float c, float d) {
    u32 v = __builtin_amdgcn_cvt_pk_fp8_f32(a, b, 0, false);
    v = __builtin_amdgcn_cvt_pk_fp8_f32(c, d, v, true);
    return v;
}

__device__ __forceinline__ float ssq4_fp8(u32 q) {
    float d0 = __builtin_amdgcn_cvt_f32_fp8(q, 0);
    float d1 = __builtin_amdgcn_cvt_f32_fp8(q, 1);
    float d2 = __builtin_amdgcn_cvt_f32_fp8(q, 2);
    float d3 = __builtin_amdgcn_cvt_f32_fp8(q, 3);
    return d0 * d0 + d1 * d1 + d2 * d2 + d3 * d3;
}

// One block per row: quantize x -> fp8 (contiguous layout, fully-coalesced
// 256B/wave stores), diag = 5*sum(q(x)^2) from QUANTIZED values, zero l_acc,
// zero the done counter.
template <bool CONVERT>
__global__ __launch_bounds__(256) void prep_kernel(const float* __restrict__ x,
                                                   u8* __restrict__ xq,
                                                   float* __restrict__ diag,
                                                   float* __restrict__ l_acc,
                                                   int* __restrict__ counters) {
    const int row = blockIdx.x;          // 0..8191
    const int tid = threadIdx.x;
    const float* src = x + (size_t)row * NHW;
    float ssum = 0.f;
#pragma unroll
    for (int p = 0; p < 4; ++p) {
        const int idx = p * 1024 + tid * 4;
        float4 v = *(const float4*)(src + idx);
        const u32 q = pk4_fp8(v.x, v.y, v.z, v.w);
        ssum += ssq4_fp8(q);
        if (CONVERT) *(u32*)(xq + (size_t)row * NHW + idx) = q;
    }
#pragma unroll
    for (int m = 1; m < 64; m <<= 1) ssum += __shfl_xor(ssum, m);
    __shared__ float red[4];
    if ((tid & 63) == 0) red[tid >> 6] = ssum;
    __syncthreads();
    if (tid == 0) {
        diag[row] = (red[0] + red[1] + red[2] + red[3]) * SCALE;
        l_acc[row] = 0.f;
        if (row == 0) counters[0] = 0;
    }
}

// Symmetric Gram, fp8 e4m3, 128x64 tiles over upper triangle (bj2 >= 2*bi),
// BK=128, double-buffered prefetch, static grid bid&7=batch (XCD L2 affinity;
// R8 proved the dynamic queue thrashes L2). R7 structure verbatim — the 7M
// LDS bank conflicts of the b64 read pattern measured as fully absorbed
// (fixing them in R9 gained nothing). ONLY addition vs R7: the last block to
// finish runs the finalize reduction inline (fence + done-counter), removing
// one dispatch + launch gap.
template <bool QSRC>
__global__ __launch_bounds__(256) void gram_kernel(const u8* __restrict__ Xq,
                                                   const float* __restrict__ Xf,
                                                   const float* __restrict__ diag,
                                                   float* __restrict__ l_acc,
                                                   float* __restrict__ num,
                                                   int* __restrict__ counters,
                                                   float* __restrict__ out) {
    __shared__ __align__(16) u8 As[2][16384];   // 128 rows * 128 B, x2
    __shared__ __align__(16) u8 Bs[2][8192];    //  64 rows * 128 B, x2
    __shared__ int s_flag;
    __shared__ float s_red[4];

    const int bid = blockIdx.x;
    const int b = bid & 7;           // batch -> XCD affinity
    const int t = bid >> 3;          // 0..71 upper-tile index

    int bi = 0;
#pragma unroll
    for (int i = 7; i >= 1; --i) {   // off(bi) = bi*(17-bi), increasing
        if (t >= i * (17 - i)) { bi = i; break; }
    }
    const int bj2 = 2 * bi + (t - bi * (17 - bi));   // 64-col block, 0..15
    const bool aliasB = (bj2 == 2 * bi) || (bj2 == 2 * bi + 1);

    const int tid  = threadIdx.x;
    const int lane = tid & 63;
    const int w    = tid >> 6;       // wave 0..3
    const int wm   = w >> 1;         // wave row-half (64 rows)
    const int wn   = w & 1;          // wave col-half (32 cols)

    // Staging: instr covers 8 rows x 8 slots. lane l -> row l>>3, slot l&7,
    // source kchunk = (l&7) ^ (l>>3).
    const int st_r  = lane >> 3;               // 0..7
    const int st_kc = (lane & 7) ^ st_r;       // source 16B-chunk

    const u8*    pA  = nullptr; const u8*    pB  = nullptr;
    const float* pAf = nullptr; const float* pBf = nullptr;
    if (QSRC) {
        const u8* baseX = Xq + (size_t)b * CCH * NHW;
        pA = baseX + (size_t)(bi * 128 + w * 32 + st_r) * NHW + st_kc * 16;
        pB = baseX + (size_t)(bj2 * 64 + w * 16 + st_r) * NHW + st_kc * 16;
    } else {
        const float* baseXf = Xf + (size_t)b * CCH * NHW;
        pAf = baseXf + (size_t)(bi * 128 + w * 32 + st_r) * NHW + st_kc * 16;
        pBf = baseXf + (size_t)(bj2 * 64 + w * 16 + st_r) * NHW + st_kc * 16;
    }

    auto stage = [&](int buf, int K0) {
        if (QSRC) {
#pragma unroll
            for (int t8 = 0; t8 < 4; ++t8)     // A: 32 rows per wave
                async_load16(pA + (size_t)(t8 * 8) * NHW + K0,
                             As[buf] + (size_t)(w * 32 + t8 * 8) * 128);
            if (!aliasB) {
#pragma unroll
                for (int t8 = 0; t8 < 2; ++t8) // B: 16 rows per wave
                    async_load16(pB + (size_t)(t8 * 8) * NHW + K0,
                                 Bs[buf] + (size_t)(w * 16 + t8 * 8) * 128);
            }
        } else {
#pragma unroll
            for (int t8 = 0; t8 < 4; ++t8) {
                const float* s = pAf + (size_t)(t8 * 8) * NHW + K0;
                float4 f0 = *(const float4*)(s);
                float4 f1 = *(const float4*)(s + 4);
                float4 f2 = *(const float4*)(s + 8);
                float4 f3 = *(const float4*)(s + 12);
                uint4v d;
                d.x = pk4_fp8(f0.x, f0.y, f0.z, f0.w);
                d.y = pk4_fp8(f1.x, f1.y, f1.z, f1.w);
                d.z = pk4_fp8(f2.x, f2.y, f2.z, f2.w);
                d.w = pk4_fp8(f3.x, f3.y, f3.z, f3.w);
                *(uint4v*)(As[buf] + (size_t)(w * 32 + t8 * 8 + st_r) * 128 + (lane & 7) * 16) = d;
            }
            if (!aliasB) {
#pragma unroll
                for (int t8 = 0; t8 < 2; ++t8) {
                    const float* s = pBf + (size_t)(t8 * 8) * NHW + K0;
                    float4 f0 = *(const float4*)(s);
                    float4 f1 = *(const float4*)(s + 4);
                    float4 f2 = *(const float4*)(s + 8);
                    float4 f3 = *(const float4*)(s + 12);
                    uint4v d;
                    d.x = pk4_fp8(f0.x, f0.y, f0.z, f0.w);
                    d.y = pk4_fp8(f1.x, f1.y, f1.z, f1.w);
                    d.z = pk4_fp8(f2.x, f2.y, f2.z, f2.w);
                    d.w = pk4_fp8(f3.x, f3.y, f3.z, f3.w);
                    *(uint4v*)(Bs[buf] + (size_t)(w * 16 + t8 * 8 + st_r) * 128 + (lane & 7) * 16) = d;
                }
            }
        }
    };

    float4v acc[4][2] = {};

    stage(0, 0);
    __syncthreads();                 // publish buffer 0

    for (int i = 0; i < NHW / 128; ++i) {
        const int cur = i & 1;
        const int K0n = (i + 1) * 128;
        if (K0n < NHW) stage(cur ^ 1, K0n);   // prefetch BEFORE compute

        const u8* Ab = As[cur];
        const u8* Bb = aliasB ? (Ab + (size_t)(bj2 - 2 * bi) * 64 * 128) : Bs[cur];
        const int q  = lane >> 4;
        const int rl = lane & 15;
#pragma unroll
        for (int s = 0; s < 4; ++s) {          // 4 k-steps of 32 elements
            const int cbase = 2 * s + (q >> 1);            // 16B chunk 0..7
            const int boff  = (int)((cbase ^ (rl & 7)) * 16 + (q & 1) * 8);
            long af[4], bf[2];
#pragma unroll
            for (int mt = 0; mt < 4; ++mt)
                af[mt] = *(const long*)(Ab + (size_t)(wm * 64 + mt * 16 + rl) * 128 + boff);
#pragma unroll
            for (int nt = 0; nt < 2; ++nt)
                bf[nt] = *(const long*)(Bb + (size_t)(wn * 32 + nt * 16 + rl) * 128 + boff);
#pragma unroll
            for (int mt = 0; mt < 4; ++mt)
#pragma unroll
                for (int nt = 0; nt < 2; ++nt)
                    acc[mt][nt] = __builtin_amdgcn_mfma_f32_16x16x32_fp8_fp8(af[mt], bf[nt], acc[mt][nt], 0, 0, 0);
        }
        __syncthreads();   // publish prefetched buffer
    }

    // ---- Epilogue ----
    const int q_  = lane >> 4;    // row-quad 0..3
    const int cl  = lane & 15;    // col within 16
    const int rowbase = bi * 128 + wm * 64;
    const int colbase = bj2 * 64 + wn * 32;
    const float* dgb = diag + b * CCH;
    float* lb = l_acc + b * CCH;

    // Row sums (upper-inclusive) + diagonal numerator
#pragma unroll
    for (int mt = 0; mt < 4; ++mt) {
#pragma unroll
        for (int reg = 0; reg < 4; ++reg) {
            const int gr = rowbase + mt * 16 + q_ * 4 + reg;
            const float dg = dgb[gr];
            float s = 0.f;
#pragma unroll
            for (int nt = 0; nt < 2; ++nt) {
                const int gc = colbase + nt * 16 + cl;
                const float e = __expf(acc[mt][nt][reg] * SCALE - dg);
                if (gr <= gc) s += e;
                if (gr == gc) num[b * CCH + gr] = e;
            }
            s += __shfl_xor(s, 1);
            s += __shfl_xor(s, 2);
            s += __shfl_xor(s, 4);
            s += __shfl_xor(s, 8);
            if (cl == 0) atomicAdd(lb + gr, s);
        }
    }

    // Column sums (strictly-upper -> transposed contribution)
#pragma unroll
    for (int nt = 0; nt < 2; ++nt) {
        const int gc = colbase + nt * 16 + cl;
        const float dgc = dgb[gc];
        float s = 0.f;
#pragma unroll
        for (int mt = 0; mt < 4; ++mt) {
#pragma unroll
            for (int reg = 0; reg < 4; ++reg) {
                const int gr = rowbase + mt * 16 + q_ * 4 + reg;
                if (gr < gc) s += __expf(acc[mt][nt][reg] * SCALE - dgc);
            }
        }
        s += __shfl_xor(s, 16);
        s += __shfl_xor(s, 32);
        if (lane < 16) atomicAdd(lb + gc, s);
    }

    // ---- Completion counter; last block finalizes ----
    __syncthreads();
    if (tid == 0) {
        __threadfence();                       // release this block's stores
        const int old = atomicAdd(counters + 0, 1);
        s_flag = (old == GRID_G - 1) ? 1 : 0;
    }
    __syncthreads();
    if (s_flag) {
        __threadfence();                       // acquire all blocks' stores
        // 8 independent accumulators for ILP (8192 rows / 256 threads = 32 iters)
        float s0 = 0.f, s1 = 0.f, s2 = 0.f, s3 = 0.f;
#pragma unroll
        for (int ib = 0; ib < 8; ib += 4) {
            const int r0 = (ib + 0) * 1024 + tid;
            const int r1 = (ib + 1) * 1024 + tid;
            const int r2 = (ib + 2) * 1024 + tid;
            const int r3 = (ib + 3) * 1024 + tid;
            const float d0 = num[r0] / l_acc[r0];
            const float d1 = num[r1] / l_acc[r1];
            const float d2 = num[r2] / l_acc[r2];
            const float d3 = num[r3] / l_acc[r3];
            s0 += -__logf(d0 + 1e-10f);
            s1 += -__logf(d1 + 1e-10f);
            s2 += -__logf(d2 + 1e-10f);
            s3 += -__logf(d3 + 1e-10f);
            const int r4 = (ib + 0) * 1024 + 256 + tid;
            const int r5 = (ib + 1) * 1024 + 256 + tid;
            const int r6 = (ib + 2) * 1024 + 256 + tid;
            const int r7 = (ib + 3) * 1024 + 256 + tid;
            const float d4 = num[r4] / l_acc[r4];
            const float d5 = num[r5] / l_acc[r5];
            const float d6 = num[r6] / l_acc[r6];
            const float d7 = num[r7] / l_acc[r7];
            s0 += -__logf(d4 + 1e-10f);
            s1 += -__logf(d5 + 1e-10f);
            s2 += -__logf(d6 + 1e-10f);
            s3 += -__logf(d7 + 1e-10f);
            const int r8 = (ib + 0) * 1024 + 512 + tid;
            const int r9 = (ib + 1) * 1024 + 512 + tid;
            const int rA = (ib + 2) * 1024 + 512 + tid;
            const int rB = (ib + 3) * 1024 + 512 + tid;
            const float d8 = num[r8] / l_acc[r8];
            const float d9 = num[r9] / l_acc[r9];
            const float dA = num[rA] / l_acc[rA];
            const float dB = num[rB] / l_acc[rB];
            s0 += -__logf(d8 + 1e-10f);
            s1 += -__logf(d9 + 1e-10f);
            s2 += -__logf(dA + 1e-10f);
            s3 += -__logf(dB + 1e-10f);
            const int rC = (ib + 0) * 1024 + 768 + tid;
            const int rD = (ib + 1) * 1024 + 768 + tid;
            const int rE = (ib + 2) * 1024 + 768 + tid;
            const int rF = (ib + 3) * 1024 + 768 + tid;
            const float dC = num[rC] / l_acc[rC];
            const float dD = num[rD] / l_acc[rD];
            const float dE = num[rE] / l_acc[rE];
            const float dF = num[rF] / l_acc[rF];
            s0 += -__logf(dC + 1e-10f);
            s1 += -__logf(dD + 1e-10f);
            s2 += -__logf(dE + 1e-10f);
            s3 += -__logf(dF + 1e-10f);
        }
        float s = (s0 + s1) + (s2 + s3);
#pragma unroll
        for (int m = 1; m < 64; m <<= 1) s += __shfl_xor(s, m);
        if ((tid & 63) == 0) s_red[tid >> 6] = s;
        __syncthreads();
        if (tid == 0)
            out[0] = (s_red[0] + s_red[1] + s_red[2] + s_red[3]) * (1.0f / (float)ROWS);
    }
}

extern "C" void kernel_launch(void* const* d_in, const int* in_sizes, int n_in,
                              void* d_out, int out_size, void* d_ws, size_t ws_size,
                              hipStream_t stream) {
    const float* x = (const float*)d_in[0];
    float* out = (float*)d_out;

    const size_t xq_bytes   = (size_t)BATCH * CCH * NHW;      // 33554432 (fp8)
    const size_t stat_bytes = (size_t)ROWS * 4;               // 32768
    const bool fast = ws_size >= xq_bytes + 3 * stat_bytes + 64;

    if (fast) {
        u8*    xq    = (u8*)d_ws;
        float* diag  = (float*)((char*)d_ws + xq_bytes);
        float* l_acc = diag + ROWS;
        float* num   = l_acc + ROWS;
        int*   cnt   = (int*)(num + ROWS);
        prep_kernel<true><<<ROWS, 256, 0, stream>>>(x, xq, diag, l_acc, cnt);
        gram_kernel<true><<<GRID_G, 256, 0, stream>>>(xq, nullptr, diag, l_acc, num, cnt, out);
    } else {
        float* diag  = (float*)d_ws;
        float* l_acc = diag + ROWS;
        float* num   = l_acc + ROWS;
        int*   cnt   = (int*)(num + ROWS);
        prep_kernel<false><<<ROWS, 256, 0, stream>>>(x, nullptr, diag, l_acc, cnt);
        gram_kernel<false><<<GRID_G, 256, 0, stream>>>(nullptr, x, diag, l_acc, num, cnt, out);
    }
}